// Round 7
// baseline (200.479 us; speedup 1.0000x reference)
//
#include <hip/hip_runtime.h>
#include <cstdint>
#include <cstddef>

#define S_LEN 2048
#define NH 16
#define HD 64
#define DM 1024
#define WIN 1024

typedef unsigned short u16;
typedef __attribute__((ext_vector_type(8))) short bf16x8;
typedef __attribute__((ext_vector_type(4))) short bf16x4;
typedef __attribute__((ext_vector_type(4))) float f32x4;
typedef __attribute__((ext_vector_type(16))) float f32x16;
typedef __attribute__((ext_vector_type(4))) u16 u16x4;
typedef __attribute__((ext_vector_type(4))) uint32_t u32x4;

__device__ inline u16 f2b(float f) {
  union { float f; uint32_t u; } x; x.f = f;
  uint32_t r = x.u + 0x7FFFu + ((x.u >> 16) & 1u);
  return (u16)(r >> 16);
}

__device__ inline uint32_t cvt_pk_bf16(float a, float b) {
  uint32_t r;
  asm("v_cvt_pk_bf16_f32 %0, %1, %2" : "=v"(r) : "v"(a), "v"(b));
  return r;
}

__device__ inline void gload16(const u16* g, u16* l) {
  __builtin_amdgcn_global_load_lds((const __attribute__((address_space(1))) void*)g,
                                   (__attribute__((address_space(3))) void*)l, 16, 0, 0);
}

// ---------------- f32 -> bf16 conversion ----------------
__global__ __launch_bounds__(256) void cvt_kernel(const float* __restrict__ src,
                                                  u16* __restrict__ dst, int n) {
  int i = (blockIdx.x * 256 + threadIdx.x) * 4;
  if (i >= n) return;
  f32x4 v = *(const f32x4*)(src + i);
  u16x4 o;
  o[0] = f2b(v[0]); o[1] = f2b(v[1]); o[2] = f2b(v[2]); o[3] = f2b(v[3]);
  *(u16x4*)(dst + i) = o;
}

// ---------------- bf16 NT GEMM: C = A * B^T + bias (R4-proven) --------------
template<int EPI>
__global__ __launch_bounds__(512)
void gemm_nt(const u16* __restrict__ A, const u16* __restrict__ B,
             const float* __restrict__ b0, const float* __restrict__ b1,
             const float* __restrict__ b2,
             float* __restrict__ outF, u16* __restrict__ outQ,
             int M, int N, int K) {
  __shared__ u16 As[128 * 32];
  __shared__ u16 Bs[128 * 32];
  const int t = threadIdx.x;
  const int lane = t & 63, wid = t >> 6;
  const int l15 = lane & 15, l4 = lane >> 4;
  const int wr = wid >> 2, wc = wid & 3;
  const int bm = blockIdx.x * 128, bn = blockIdx.y * 128;
  const int sr = t >> 2, sc = (t & 3) << 3;
  const u16* Ag = A + (size_t)(bm + sr) * K + sc;
  const u16* Bg = B + (size_t)(bn + sr) * K + sc;
  u16* Asl = As + wid * 512;
  u16* Bsl = Bs + wid * 512;
  f32x4 acc[4][2];
#pragma unroll
  for (int i = 0; i < 4; i++)
#pragma unroll
    for (int j = 0; j < 2; j++) acc[i][j] = (f32x4){0.f, 0.f, 0.f, 0.f};

  for (int kb = 0; kb < K; kb += 32) {
    __syncthreads();
    gload16(Ag + kb, Asl);
    gload16(Bg + kb, Bsl);
    __syncthreads();
    bf16x8 af[4], bq[2];
#pragma unroll
    for (int mi = 0; mi < 4; mi++)
      af[mi] = *(bf16x8*)&As[(wr * 64 + mi * 16 + l15) * 32 + l4 * 8];
#pragma unroll
    for (int ni = 0; ni < 2; ni++)
      bq[ni] = *(bf16x8*)&Bs[(wc * 32 + ni * 16 + l15) * 32 + l4 * 8];
#pragma unroll
    for (int mi = 0; mi < 4; mi++)
#pragma unroll
      for (int ni = 0; ni < 2; ni++)
        acc[mi][ni] = __builtin_amdgcn_mfma_f32_16x16x32_bf16(af[mi], bq[ni], acc[mi][ni], 0, 0, 0);
  }

  const int cb = bn >> 10;
  const float* bp = (EPI == 0) ? b0 : (cb == 0 ? b0 : (cb == 1 ? b1 : b2));
#pragma unroll
  for (int mi = 0; mi < 4; mi++) {
#pragma unroll
    for (int ni = 0; ni < 2; ni++) {
#pragma unroll
      for (int r = 0; r < 4; r++) {
        int row = bm + wr * 64 + mi * 16 + l4 * 4 + r;
        int col = bn + wc * 32 + ni * 16 + l15;
        float v = acc[mi][ni][r] + bp[col & (DM - 1)];
        if (EPI == 0) {
          outF[(size_t)row * N + col] = v;
        } else {
          int b = row >> 11, s = row & (S_LEN - 1);
          int which = col >> 10, cw = col & (DM - 1);
          int h = cw >> 6, d = cw & (HD - 1);
          outQ[(size_t)which * 4194304 +
               (((size_t)(b * NH + h)) * S_LEN + s) * HD + d] = f2b(v);
        }
      }
    }
  }
}

// ---------------- V transpose: [BH][S][64] -> [BH][64][S] (R4-proven) -------
__global__ __launch_bounds__(256)
void transpose_v(const u16* __restrict__ V, u16* __restrict__ Vt) {
  const int bh = blockIdx.y;
  const int s0 = blockIdx.x * 64;
  __shared__ u16 tile[64][72];
  const int t = threadIdx.x;
  const u16* src = V + ((size_t)bh * S_LEN + s0) * HD;
#pragma unroll
  for (int i = 0; i < 2; i++) {
    int e = t * 8 + i * 2048;
    int r = e >> 6, c = e & 63;
    *(bf16x8*)&tile[r][c] = *(const bf16x8*)(src + e);
  }
  __syncthreads();
  u16* dst = Vt + (size_t)bh * HD * S_LEN + s0;
#pragma unroll
  for (int i = 0; i < 2; i++) {
    int e = t * 8 + i * 2048;
    int d = e >> 6, s = e & 63;
    bf16x8 tmp;
#pragma unroll
    for (int j = 0; j < 8; j++) tmp[j] = (short)tile[s + j][d];
    *(bf16x8*)&dst[(size_t)d * S_LEN + s] = tmp;
  }
}

// ---------------- attention: R4 per-tile math, intra-block split-K ----------
// Block = 8 waves = one (bh, 32-row q-tile). Wave w owns K-tiles lo+64*(w+8i).
// Per-tile math (loadK/vfrag/process_tile) is VERBATIM the R4-passing code.
// Partial (O,m,l) flash-combined through LDS; wave 0 stores with R4 epilogue.
struct KTile { bf16x8 f[2][4]; };

__device__ __forceinline__ KTile loadK(const u16* __restrict__ Kp, int kb, int l31, int hi) {
  KTile k;
#pragma unroll
  for (int s = 0; s < 2; s++)
#pragma unroll
    for (int f = 0; f < 4; f++)
      k.f[s][f] = *(const bf16x8*)(Kp + (size_t)(kb + 32 * s + l31) * HD + 16 * f + 8 * hi);
  return k;
}

__device__ __forceinline__ bf16x8 vfrag(const u16* __restrict__ base) {
  bf16x4 a = *(const bf16x4*)base;
  bf16x4 b = *(const bf16x4*)(base + 8);
  bf16x8 v;
  v[0] = a[0]; v[1] = a[1]; v[2] = a[2]; v[3] = a[3];
  v[4] = b[0]; v[5] = b[1]; v[6] = b[2]; v[7] = b[3];
  return v;
}

__device__ __forceinline__ void process_tile(
    int kb, const KTile& kt, const u16* __restrict__ Vp, const bf16x8 qf[4],
    int qw, int l31, int hi, float slope2,
    float& m, float& lsum, f32x16& O0, f32x16& O1) {
  bf16x8 vf[2][4];
#pragma unroll
  for (int d = 0; d < 2; d++)
#pragma unroll
    for (int ks = 0; ks < 4; ks++)
      vf[d][ks] = vfrag(Vp + (size_t)(32 * d + l31) * S_LEN + kb + 16 * ks + 4 * hi);

  f32x16 st0, st1;
#pragma unroll
  for (int r = 0; r < 16; r++) { st0[r] = 0.f; st1[r] = 0.f; }
#pragma unroll
  for (int f = 0; f < 4; f++) {
    st0 = __builtin_amdgcn_mfma_f32_32x32x16_bf16(kt.f[0][f], qf[f], st0, 0, 0, 0);
    st1 = __builtin_amdgcn_mfma_f32_32x32x16_bf16(kt.f[1][f], qf[f], st1, 0, 0, 0);
  }

  const float qks = 0.125f * 1.44269504f;
  const int dkb = kb + 4 * hi - (qw + l31);
  const bool interior = (kb + 63 <= qw) && (kb >= qw - (WIN - 32));
  float p0[16], p1[16];
#pragma unroll
  for (int r = 0; r < 16; r++) {
    int off = (r & 3) + 8 * (r >> 2);
    int dk0 = dkb + off, dk1 = dkb + 32 + off;
    float s0 = st0[r] * qks + slope2 * (float)dk0;
    float s1 = st1[r] * qks + slope2 * (float)dk1;
    if (!interior) {
      s0 = (dk0 > 0 || dk0 <= -WIN) ? -3e38f : s0;
      s1 = (dk1 > 0 || dk1 <= -WIN) ? -3e38f : s1;
    }
    p0[r] = s0; p1[r] = s1;
  }
  float t8[8];
#pragma unroll
  for (int r = 0; r < 8; r++)
    t8[r] = fmaxf(fmaxf(p0[r], p0[r + 8]), fmaxf(p1[r], p1[r + 8]));
#pragma unroll
  for (int r = 0; r < 4; r++) t8[r] = fmaxf(t8[r], t8[r + 4]);
  float rmax = fmaxf(fmaxf(t8[0], t8[1]), fmaxf(t8[2], t8[3]));
  rmax = fmaxf(rmax, __shfl_xor(rmax, 32, 64));
  float mn = fmaxf(fmaxf(m, rmax), -1e30f);
  float sc = exp2f(m - mn);
  m = mn;
#pragma unroll
  for (int r = 0; r < 16; r++) {
    p0[r] = exp2f(p0[r] - mn);
    p1[r] = exp2f(p1[r] - mn);
  }
  float a8[8];
#pragma unroll
  for (int r = 0; r < 8; r++)
    a8[r] = (p0[r] + p0[r + 8]) + (p1[r] + p1[r + 8]);
#pragma unroll
  for (int r = 0; r < 4; r++) a8[r] += a8[r + 4];
  float rsum = (a8[0] + a8[1]) + (a8[2] + a8[3]);
  rsum += __shfl_xor(rsum, 32, 64);
  lsum = lsum * sc + rsum;

  auto pk8 = [&](const float (&pp)[16], int base) -> bf16x8 {
    u32x4 w4;
    w4[0] = cvt_pk_bf16(pp[base + 0], pp[base + 1]);
    w4[1] = cvt_pk_bf16(pp[base + 2], pp[base + 3]);
    w4[2] = cvt_pk_bf16(pp[base + 4], pp[base + 5]);
    w4[3] = cvt_pk_bf16(pp[base + 6], pp[base + 7]);
    return __builtin_bit_cast(bf16x8, w4);
  };
  bf16x8 pb[4];
  pb[0] = pk8(p0, 0); pb[1] = pk8(p0, 8);
  pb[2] = pk8(p1, 0); pb[3] = pk8(p1, 8);

#pragma unroll
  for (int r = 0; r < 16; r++) { O0[r] *= sc; O1[r] *= sc; }
#pragma unroll
  for (int ks = 0; ks < 4; ks++) {
    O0 = __builtin_amdgcn_mfma_f32_32x32x16_bf16(vf[0][ks], pb[ks], O0, 0, 0, 0);
    O1 = __builtin_amdgcn_mfma_f32_32x32x16_bf16(vf[1][ks], pb[ks], O1, 0, 0, 0);
  }
}

__global__ __launch_bounds__(512, 4)
void attn_kernel(const u16* __restrict__ Q, const u16* __restrict__ Kg,
                 const u16* __restrict__ Vt, u16* __restrict__ attn) {
  __shared__ float comb[8][64][37];
  const int bid = blockIdx.x;
  const int job = (bid & 7) * 256 + (bid >> 3);  // XCD swizzle (2048 % 8 == 0)
  const int bh = job >> 6, qt = job & 63;
  const int b = bh >> 4, h = bh & 15;
  const int tid = threadIdx.x;
  const int wid = tid >> 6, lane = tid & 63;
  const int l31 = lane & 31, hi = lane >> 5;
  const int qw = qt * 32;
  const u16* Qp = Q + (size_t)bh * (S_LEN * HD);
  const u16* Kp = Kg + (size_t)bh * (S_LEN * HD);
  const u16* Vp = Vt + (size_t)bh * (HD * S_LEN);

  bf16x8 qf[4];
#pragma unroll
  for (int f = 0; f < 4; f++)
    qf[f] = *(const bf16x8*)(Qp + (size_t)(qw + l31) * HD + 16 * f + 8 * hi);

  const float slope2 = exp2f(-0.5f * (float)(h + 1)) * 1.44269504f;
  float m = -3e38f, lsum = 0.f;
  f32x16 O0, O1;
#pragma unroll
  for (int r = 0; r < 16; r++) { O0[r] = 0.f; O1[r] = 0.f; }

  int lo = qw - (WIN - 1); if (lo < 0) lo = 0; lo &= ~63;
  const int last = (qw + 31) & ~63;

  // wave wid owns K-tiles lo + 64*(wid + 8*i)
  for (int kb = lo + wid * 64; kb <= last; kb += 512) {
    KTile kt = loadK(Kp, kb, l31, hi);
    process_tile(kb, kt, Vp, qf, qw, l31, hi, slope2, m, lsum, O0, O1);
  }

  // write partial (O, m, l) to LDS
  float* c = &comb[wid][lane][0];
#pragma unroll
  for (int r = 0; r < 16; r++) { c[r] = O0[r]; c[16 + r] = O1[r]; }
  c[32] = m; c[33] = lsum;
  __syncthreads();
  if (wid != 0) return;

  // wave 0: flash-combine the 8 partials (lane-local across waves)
  for (int w = 1; w < 8; w++) {
    const float* cw = &comb[w][lane][0];
    float mw = cw[32], lw = cw[33];
    float M = fmaxf(m, mw);
    float wa = exp2f(m - M), wb = exp2f(mw - M);
#pragma unroll
    for (int r = 0; r < 16; r++) {
      O0[r] = O0[r] * wa + cw[r] * wb;
      O1[r] = O1[r] * wa + cw[16 + r] * wb;
    }
    lsum = lsum * wa + lw * wb;
    m = M;
  }

  const float invl = 1.f / lsum;
  u16* op = attn + ((size_t)(b * S_LEN) + qw + l31) * DM + h * HD;
#pragma unroll
  for (int r = 0; r < 16; r += 2) {
    int d0 = (r & 3) + 8 * (r >> 2) + 4 * hi;
    uint32_t w0 = cvt_pk_bf16(O0[r] * invl, O0[r + 1] * invl);
    uint32_t w1 = cvt_pk_bf16(O1[r] * invl, O1[r + 1] * invl);
    *(uint32_t*)(op + d0) = w0;
    *(uint32_t*)(op + 32 + d0) = w1;
  }
}

// ---------------- launch ----------------
extern "C" void kernel_launch(void* const* d_in, const int* in_sizes, int n_in,
                              void* d_out, int out_size, void* d_ws, size_t ws_size,
                              hipStream_t stream) {
  const float* x  = (const float*)d_in[0];
  const float* wq = (const float*)d_in[1];
  const float* bq = (const float*)d_in[2];
  const float* wk = (const float*)d_in[3];
  const float* bk = (const float*)d_in[4];
  const float* wv = (const float*)d_in[5];
  const float* bv = (const float*)d_in[6];
  const float* wo = (const float*)d_in[7];
  const float* bo = (const float*)d_in[8];

  char* ws = (char*)d_ws;
  u16* xb    = (u16*)(ws);                  // 8 MB  [4096][1024]
  u16* wqkvb = (u16*)(ws + 8388608);        // 6 MB  [3072][1024]
  u16* wob   = (u16*)(ws + 14680064);       // 2 MB  [1024][1024]
  u16* QKVb  = (u16*)(ws + 16777216);       // 24 MB: Q|K|V row layout [bh][s][64]
  u16* Vtb   = (u16*)(ws + 41943040);       // 8 MB  [BH][64][S]
  u16* Ab    = (u16*)(ws + 50331648);       // 8 MB  [B*S][1024]
  u16* Vb    = QKVb + 2 * 4194304;

  const int M = 4096;

  cvt_kernel<<<dim3(4096), dim3(256), 0, stream>>>(x, xb, 4194304);
  cvt_kernel<<<dim3(1024), dim3(256), 0, stream>>>(wq, wqkvb,           1048576);
  cvt_kernel<<<dim3(1024), dim3(256), 0, stream>>>(wk, wqkvb + 1048576, 1048576);
  cvt_kernel<<<dim3(1024), dim3(256), 0, stream>>>(wv, wqkvb + 2097152, 1048576);
  cvt_kernel<<<dim3(1024), dim3(256), 0, stream>>>(wo, wob,             1048576);

  gemm_nt<1><<<dim3(32, 24), dim3(512), 0, stream>>>(xb, wqkvb, bq, bk, bv,
                                                     nullptr, QKVb, M, 3072, DM);

  transpose_v<<<dim3(32, 32), dim3(256), 0, stream>>>(Vb, Vtb);

  attn_kernel<<<dim3(2048), dim3(512), 0, stream>>>(QKVb, QKVb + 4194304, Vtb, Ab);

  gemm_nt<0><<<dim3(32, 8), dim3(512), 0, stream>>>(Ab, wob, bo, nullptr, nullptr,
                                                    (float*)d_out, nullptr, M, DM, DM);
}

// Round 8
// 178.516 us; speedup vs baseline: 1.1230x; 1.1230x over previous
//
#include <hip/hip_runtime.h>
#include <cstdint>
#include <cstddef>

#define S_LEN 2048
#define NH 16
#define HD 64
#define DM 1024
#define WIN 1024

typedef unsigned short u16;
typedef __attribute__((ext_vector_type(8))) short bf16x8;
typedef __attribute__((ext_vector_type(4))) short bf16x4;
typedef __attribute__((ext_vector_type(4))) float f32x4;
typedef __attribute__((ext_vector_type(16))) float f32x16;
typedef __attribute__((ext_vector_type(4))) u16 u16x4;
typedef __attribute__((ext_vector_type(4))) uint32_t u32x4;

__device__ inline u16 f2b(float f) {
  union { float f; uint32_t u; } x; x.f = f;
  uint32_t r = x.u + 0x7FFFu + ((x.u >> 16) & 1u);
  return (u16)(r >> 16);
}

__device__ inline uint32_t cvt_pk_bf16(float a, float b) {
  uint32_t r;
  asm("v_cvt_pk_bf16_f32 %0, %1, %2" : "=v"(r) : "v"(a), "v"(b));
  return r;
}

__device__ inline void gload16(const void* g, void* l) {
  __builtin_amdgcn_global_load_lds((const __attribute__((address_space(1))) void*)g,
                                   (__attribute__((address_space(3))) void*)l, 16, 0, 0);
}

// ---------------- f32 -> bf16 conversion ----------------
__global__ __launch_bounds__(256) void cvt_kernel(const float* __restrict__ src,
                                                  u16* __restrict__ dst, int n) {
  int i = (blockIdx.x * 256 + threadIdx.x) * 4;
  if (i >= n) return;
  f32x4 v = *(const f32x4*)(src + i);
  u16x4 o;
  o[0] = f2b(v[0]); o[1] = f2b(v[1]); o[2] = f2b(v[2]); o[3] = f2b(v[3]);
  *(u16x4*)(dst + i) = o;
}

// ---------------- bf16 NT GEMM: C = A * B^T + bias (R4-proven) --------------
template<int EPI>
__global__ __launch_bounds__(512)
void gemm_nt(const u16* __restrict__ A, const u16* __restrict__ B,
             const float* __restrict__ b0, const float* __restrict__ b1,
             const float* __restrict__ b2,
             float* __restrict__ outF, u16* __restrict__ outQ,
             int M, int N, int K) {
  __shared__ u16 As[128 * 32];
  __shared__ u16 Bs[128 * 32];
  const int t = threadIdx.x;
  const int lane = t & 63, wid = t >> 6;
  const int l15 = lane & 15, l4 = lane >> 4;
  const int wr = wid >> 2, wc = wid & 3;
  const int bm = blockIdx.x * 128, bn = blockIdx.y * 128;
  const int sr = t >> 2, sc = (t & 3) << 3;
  const u16* Ag = A + (size_t)(bm + sr) * K + sc;
  const u16* Bg = B + (size_t)(bn + sr) * K + sc;
  u16* Asl = As + wid * 512;
  u16* Bsl = Bs + wid * 512;
  f32x4 acc[4][2];
#pragma unroll
  for (int i = 0; i < 4; i++)
#pragma unroll
    for (int j = 0; j < 2; j++) acc[i][j] = (f32x4){0.f, 0.f, 0.f, 0.f};

  for (int kb = 0; kb < K; kb += 32) {
    __syncthreads();
    gload16(Ag + kb, Asl);
    gload16(Bg + kb, Bsl);
    __syncthreads();
    bf16x8 af[4], bq[2];
#pragma unroll
    for (int mi = 0; mi < 4; mi++)
      af[mi] = *(bf16x8*)&As[(wr * 64 + mi * 16 + l15) * 32 + l4 * 8];
#pragma unroll
    for (int ni = 0; ni < 2; ni++)
      bq[ni] = *(bf16x8*)&Bs[(wc * 32 + ni * 16 + l15) * 32 + l4 * 8];
#pragma unroll
    for (int mi = 0; mi < 4; mi++)
#pragma unroll
      for (int ni = 0; ni < 2; ni++)
        acc[mi][ni] = __builtin_amdgcn_mfma_f32_16x16x32_bf16(af[mi], bq[ni], acc[mi][ni], 0, 0, 0);
  }

  const int cb = bn >> 10;
  const float* bp = (EPI == 0) ? b0 : (cb == 0 ? b0 : (cb == 1 ? b1 : b2));
#pragma unroll
  for (int mi = 0; mi < 4; mi++) {
#pragma unroll
    for (int ni = 0; ni < 2; ni++) {
#pragma unroll
      for (int r = 0; r < 4; r++) {
        int row = bm + wr * 64 + mi * 16 + l4 * 4 + r;
        int col = bn + wc * 32 + ni * 16 + l15;
        float v = acc[mi][ni][r] + bp[col & (DM - 1)];
        if (EPI == 0) {
          outF[(size_t)row * N + col] = v;
        } else {
          int b = row >> 11, s = row & (S_LEN - 1);
          int which = col >> 10, cw = col & (DM - 1);
          int h = cw >> 6, d = cw & (HD - 1);
          outQ[(size_t)which * 4194304 +
               (((size_t)(b * NH + h)) * S_LEN + s) * HD + d] = f2b(v);
        }
      }
    }
  }
}

// ---------------- V transpose: [BH][S][64] -> [BH][64][S] (R4-proven) -------
__global__ __launch_bounds__(256)
void transpose_v(const u16* __restrict__ V, u16* __restrict__ Vt) {
  const int bh = blockIdx.y;
  const int s0 = blockIdx.x * 64;
  __shared__ u16 tile[64][72];
  const int t = threadIdx.x;
  const u16* src = V + ((size_t)bh * S_LEN + s0) * HD;
#pragma unroll
  for (int i = 0; i < 2; i++) {
    int e = t * 8 + i * 2048;
    int r = e >> 6, c = e & 63;
    *(bf16x8*)&tile[r][c] = *(const bf16x8*)(src + e);
  }
  __syncthreads();
  u16* dst = Vt + (size_t)bh * HD * S_LEN + s0;
#pragma unroll
  for (int i = 0; i < 2; i++) {
    int e = t * 8 + i * 2048;
    int d = e >> 6, s = e & 63;
    bf16x8 tmp;
#pragma unroll
    for (int j = 0; j < 8; j++) tmp[j] = (short)tile[s + j][d];
    *(bf16x8*)&dst[(size_t)d * S_LEN + s] = tmp;
  }
}

// ---------------- attention: LDS-staged K/V tiles, R4 register math ---------
// Block = 4 waves, 128 q-rows of one bh; wave w owns rows qw=q0+32w (R4 style).
// K tile [64 keys][128B] and Vt tile [64 d][128B] staged to LDS double-buffered
// via global_load_lds (linear dest, inverse-swizzled source, rule #21); reads
// use byte ^= (row&7)<<4 -> bank-floor access. Values delivered to registers
// are bit-identical to the R4-passing kernel.
struct KTile { bf16x8 f[2][4]; };

__device__ __forceinline__ KTile loadK_lds(const u16* __restrict__ Kl, int l31, int hi) {
  KTile k;
  const int x = l31 & 7;
#pragma unroll
  for (int s = 0; s < 2; s++)
#pragma unroll
    for (int f = 0; f < 4; f++)
      k.f[s][f] = *(const bf16x8*)&Kl[(32 * s + l31) * 64 + (((2 * f + hi) ^ x) << 3)];
  return k;
}

__device__ __forceinline__ bf16x8 vfrag_lds(const u16* __restrict__ Vl, int d, int ks,
                                            int l31, int hi) {
  const int row = 32 * d + l31, x = l31 & 7;
  bf16x4 a = *(const bf16x4*)&Vl[row * 64 + (((2 * ks) ^ x) << 3) + 4 * hi];
  bf16x4 b = *(const bf16x4*)&Vl[row * 64 + (((2 * ks + 1) ^ x) << 3) + 4 * hi];
  bf16x8 v;
  v[0] = a[0]; v[1] = a[1]; v[2] = a[2]; v[3] = a[3];
  v[4] = b[0]; v[5] = b[1]; v[6] = b[2]; v[7] = b[3];
  return v;
}

// stage one 64-key tile: K rows contiguous (8KB), Vt rows strided 4096B.
__device__ __forceinline__ void stage_tiles(const char* __restrict__ Kg,
                                            const char* __restrict__ Vg,
                                            u16* __restrict__ Kl, u16* __restrict__ Vl,
                                            int t) {
#pragma unroll
  for (int shot = 0; shot < 2; shot++) {
    int o = shot * 4096 + t * 16;
    int sw = ((o >> 7) & 7) << 4;
    gload16(Kg + (o ^ sw), (char*)Kl + o);
    gload16(Vg + (size_t)(o >> 7) * 4096 + ((o & 127) ^ sw), (char*)Vl + o);
  }
}

__device__ __forceinline__ void process_tile(
    int kb, const KTile& kt, const u16* __restrict__ Vl, const bf16x8 qf[4],
    int qw, int l31, int hi, float slope2,
    float& m, float& lsum, f32x16& O0, f32x16& O1) {
  bf16x8 vf[2][4];
#pragma unroll
  for (int d = 0; d < 2; d++)
#pragma unroll
    for (int ks = 0; ks < 4; ks++)
      vf[d][ks] = vfrag_lds(Vl, d, ks, l31, hi);

  f32x16 st0, st1;
#pragma unroll
  for (int r = 0; r < 16; r++) { st0[r] = 0.f; st1[r] = 0.f; }
#pragma unroll
  for (int f = 0; f < 4; f++) {
    st0 = __builtin_amdgcn_mfma_f32_32x32x16_bf16(kt.f[0][f], qf[f], st0, 0, 0, 0);
    st1 = __builtin_amdgcn_mfma_f32_32x32x16_bf16(kt.f[1][f], qf[f], st1, 0, 0, 0);
  }

  const float qks = 0.125f * 1.44269504f;
  const int dkb = kb + 4 * hi - (qw + l31);
  const bool interior = (kb + 63 <= qw) && (kb >= qw - (WIN - 32));
  float p0[16], p1[16];
#pragma unroll
  for (int r = 0; r < 16; r++) {
    int off = (r & 3) + 8 * (r >> 2);
    int dk0 = dkb + off, dk1 = dkb + 32 + off;
    float s0 = st0[r] * qks + slope2 * (float)dk0;
    float s1 = st1[r] * qks + slope2 * (float)dk1;
    if (!interior) {
      s0 = (dk0 > 0 || dk0 <= -WIN) ? -3e38f : s0;
      s1 = (dk1 > 0 || dk1 <= -WIN) ? -3e38f : s1;
    }
    p0[r] = s0; p1[r] = s1;
  }
  float t8[8];
#pragma unroll
  for (int r = 0; r < 8; r++)
    t8[r] = fmaxf(fmaxf(p0[r], p0[r + 8]), fmaxf(p1[r], p1[r + 8]));
#pragma unroll
  for (int r = 0; r < 4; r++) t8[r] = fmaxf(t8[r], t8[r + 4]);
  float rmax = fmaxf(fmaxf(t8[0], t8[1]), fmaxf(t8[2], t8[3]));
  rmax = fmaxf(rmax, __shfl_xor(rmax, 32, 64));
  float mn = fmaxf(fmaxf(m, rmax), -1e30f);
  float sc = exp2f(m - mn);
  m = mn;
#pragma unroll
  for (int r = 0; r < 16; r++) {
    p0[r] = exp2f(p0[r] - mn);
    p1[r] = exp2f(p1[r] - mn);
  }
  float a8[8];
#pragma unroll
  for (int r = 0; r < 8; r++)
    a8[r] = (p0[r] + p0[r + 8]) + (p1[r] + p1[r + 8]);
#pragma unroll
  for (int r = 0; r < 4; r++) a8[r] += a8[r + 4];
  float rsum = (a8[0] + a8[1]) + (a8[2] + a8[3]);
  rsum += __shfl_xor(rsum, 32, 64);
  lsum = lsum * sc + rsum;

  auto pk8 = [&](const float (&pp)[16], int base) -> bf16x8 {
    u32x4 w4;
    w4[0] = cvt_pk_bf16(pp[base + 0], pp[base + 1]);
    w4[1] = cvt_pk_bf16(pp[base + 2], pp[base + 3]);
    w4[2] = cvt_pk_bf16(pp[base + 4], pp[base + 5]);
    w4[3] = cvt_pk_bf16(pp[base + 6], pp[base + 7]);
    return __builtin_bit_cast(bf16x8, w4);
  };
  bf16x8 pb[4];
  pb[0] = pk8(p0, 0); pb[1] = pk8(p0, 8);
  pb[2] = pk8(p1, 0); pb[3] = pk8(p1, 8);

#pragma unroll
  for (int r = 0; r < 16; r++) { O0[r] *= sc; O1[r] *= sc; }
#pragma unroll
  for (int ks = 0; ks < 4; ks++) {
    O0 = __builtin_amdgcn_mfma_f32_32x32x16_bf16(vf[0][ks], pb[ks], O0, 0, 0, 0);
    O1 = __builtin_amdgcn_mfma_f32_32x32x16_bf16(vf[1][ks], pb[ks], O1, 0, 0, 0);
  }
}

__global__ __launch_bounds__(256, 4)
void attn_kernel(const u16* __restrict__ Q, const u16* __restrict__ Kg,
                 const u16* __restrict__ Vt, u16* __restrict__ attn) {
  __shared__ __align__(16) u16 Klds[2][4096];
  __shared__ __align__(16) u16 Vlds[2][4096];
  const int bid = blockIdx.x;
  const int job = (bid & 7) * 64 + (bid >> 3);   // XCD swizzle (512 % 8 == 0)
  const int bh = job >> 4, qb = job & 15;
  const int b = bh >> 4, h = bh & 15;
  const int tid = threadIdx.x;
  const int wid = tid >> 6, lane = tid & 63;
  const int l31 = lane & 31, hi = lane >> 5;
  const int q0 = qb << 7;
  const int qw = q0 + 32 * wid;
  const u16* Qp = Q + (size_t)bh * (S_LEN * HD);
  const char* Kbase = (const char*)(Kg + (size_t)bh * (S_LEN * HD));
  const char* Vbase = (const char*)(Vt + (size_t)bh * (HD * S_LEN));

  bf16x8 qf[4];
#pragma unroll
  for (int f = 0; f < 4; f++)
    qf[f] = *(const bf16x8*)(Qp + (size_t)(qw + l31) * HD + 16 * f + 8 * hi);

  const float slope2 = exp2f(-0.5f * (float)(h + 1)) * 1.44269504f;
  float m = -3e38f, lsum = 0.f;
  f32x16 O0, O1;
#pragma unroll
  for (int r = 0; r < 16; r++) { O0[r] = 0.f; O1[r] = 0.f; }

  // block-union tile range; per-wave active range
  int lo_u = q0 - (WIN - 1); if (lo_u < 0) lo_u = 0; lo_u &= ~63;
  const int hi_u = (q0 + 127) & ~63;
  int lo_w = qw - (WIN - 1); if (lo_w < 0) lo_w = 0; lo_w &= ~63;
  const int last_w = (qw + 31) & ~63;

  stage_tiles(Kbase + (size_t)lo_u * 128, Vbase + (size_t)lo_u * 2,
              Klds[0], Vlds[0], tid);
  int cur = 0;
  for (int kb = lo_u; kb <= hi_u; kb += 64) {
    __syncthreads();   // tile kb resident in Klds/Vlds[cur]; prev reads done
    if (kb + 64 <= hi_u)
      stage_tiles(Kbase + (size_t)(kb + 64) * 128, Vbase + (size_t)(kb + 64) * 2,
                  Klds[cur ^ 1], Vlds[cur ^ 1], tid);
    if (kb >= lo_w && kb <= last_w) {   // wave-uniform branch
      KTile kt = loadK_lds(Klds[cur], l31, hi);
      process_tile(kb, kt, Vlds[cur], qf, qw, l31, hi, slope2, m, lsum, O0, O1);
    }
    cur ^= 1;
  }

  const float invl = 1.f / lsum;
  u16* op = attn + ((size_t)(b * S_LEN) + qw + l31) * DM + h * HD;
#pragma unroll
  for (int r = 0; r < 16; r += 2) {
    int d0 = (r & 3) + 8 * (r >> 2) + 4 * hi;
    uint32_t w0 = cvt_pk_bf16(O0[r] * invl, O0[r + 1] * invl);
    uint32_t w1 = cvt_pk_bf16(O1[r] * invl, O1[r + 1] * invl);
    *(uint32_t*)(op + d0) = w0;
    *(uint32_t*)(op + 32 + d0) = w1;
  }
}

// ---------------- launch ----------------
extern "C" void kernel_launch(void* const* d_in, const int* in_sizes, int n_in,
                              void* d_out, int out_size, void* d_ws, size_t ws_size,
                              hipStream_t stream) {
  const float* x  = (const float*)d_in[0];
  const float* wq = (const float*)d_in[1];
  const float* bq = (const float*)d_in[2];
  const float* wk = (const float*)d_in[3];
  const float* bk = (const float*)d_in[4];
  const float* wv = (const float*)d_in[5];
  const float* bv = (const float*)d_in[6];
  const float* wo = (const float*)d_in[7];
  const float* bo = (const float*)d_in[8];

  char* ws = (char*)d_ws;
  u16* xb    = (u16*)(ws);                  // 8 MB  [4096][1024]
  u16* wqkvb = (u16*)(ws + 8388608);        // 6 MB  [3072][1024]
  u16* wob   = (u16*)(ws + 14680064);       // 2 MB  [1024][1024]
  u16* QKVb  = (u16*)(ws + 16777216);       // 24 MB: Q|K|V row layout [bh][s][64]
  u16* Vtb   = (u16*)(ws + 41943040);       // 8 MB  [BH][64][S]
  u16* Ab    = (u16*)(ws + 50331648);       // 8 MB  [B*S][1024]
  u16* Vb    = QKVb + 2 * 4194304;

  const int M = 4096;

  cvt_kernel<<<dim3(4096), dim3(256), 0, stream>>>(x, xb, 4194304);
  cvt_kernel<<<dim3(1024), dim3(256), 0, stream>>>(wq, wqkvb,           1048576);
  cvt_kernel<<<dim3(1024), dim3(256), 0, stream>>>(wk, wqkvb + 1048576, 1048576);
  cvt_kernel<<<dim3(1024), dim3(256), 0, stream>>>(wv, wqkvb + 2097152, 1048576);
  cvt_kernel<<<dim3(1024), dim3(256), 0, stream>>>(wo, wob,             1048576);

  gemm_nt<1><<<dim3(32, 24), dim3(512), 0, stream>>>(xb, wqkvb, bq, bk, bv,
                                                     nullptr, QKVb, M, 3072, DM);

  transpose_v<<<dim3(32, 32), dim3(256), 0, stream>>>(Vb, Vtb);

  attn_kernel<<<dim3(512), dim3(256), 0, stream>>>(QKVb, QKVb + 4194304, Vtb, Ab);

  gemm_nt<0><<<dim3(32, 8), dim3(512), 0, stream>>>(Ab, wob, bo, nullptr, nullptr,
                                                    (float*)d_out, nullptr, M, DM, DM);
}

// Round 9
// 129.892 us; speedup vs baseline: 1.5434x; 1.3743x over previous
//
#include <hip/hip_runtime.h>
#include <cstdint>
#include <cstddef>

#define S_LEN 2048
#define NH 16
#define HD 64
#define DM 1024
#define WIN 1024

typedef unsigned short u16;
typedef __attribute__((ext_vector_type(8))) short bf16x8;
typedef __attribute__((ext_vector_type(4))) short bf16x4;
typedef __attribute__((ext_vector_type(4))) float f32x4;
typedef __attribute__((ext_vector_type(4))) u16 u16x4;
typedef __attribute__((ext_vector_type(2))) uint32_t u32x2;
typedef __attribute__((ext_vector_type(4))) uint32_t u32x4;

__device__ inline u16 f2b(float f) {
  union { float f; uint32_t u; } x; x.f = f;
  uint32_t r = x.u + 0x7FFFu + ((x.u >> 16) & 1u);
  return (u16)(r >> 16);
}

__device__ inline uint32_t cvt_pk_bf16(float a, float b) {
  uint32_t r;
  asm("v_cvt_pk_bf16_f32 %0, %1, %2" : "=v"(r) : "v"(a), "v"(b));
  return r;
}

__device__ inline void gload16(const void* g, void* l) {
  __builtin_amdgcn_global_load_lds((const __attribute__((address_space(1))) void*)g,
                                   (__attribute__((address_space(3))) void*)l, 16, 0, 0);
}

// ---------------- f32 -> bf16 conversion ----------------
__global__ __launch_bounds__(256) void cvt_kernel(const float* __restrict__ src,
                                                  u16* __restrict__ dst, int n) {
  int i = (blockIdx.x * 256 + threadIdx.x) * 4;
  if (i >= n) return;
  f32x4 v = *(const f32x4*)(src + i);
  u16x4 o;
  o[0] = f2b(v[0]); o[1] = f2b(v[1]); o[2] = f2b(v[2]); o[3] = f2b(v[3]);
  *(u16x4*)(dst + i) = o;
}

// ---------------- bf16 NT GEMM: C = A * B^T + bias (R4-proven) --------------
template<int EPI>
__global__ __launch_bounds__(512)
void gemm_nt(const u16* __restrict__ A, const u16* __restrict__ B,
             const float* __restrict__ b0, const float* __restrict__ b1,
             const float* __restrict__ b2,
             float* __restrict__ outF, u16* __restrict__ outQ,
             int M, int N, int K) {
  __shared__ u16 As[128 * 32];
  __shared__ u16 Bs[128 * 32];
  const int t = threadIdx.x;
  const int lane = t & 63, wid = t >> 6;
  const int l15 = lane & 15, l4 = lane >> 4;
  const int wr = wid >> 2, wc = wid & 3;
  const int bm = blockIdx.x * 128, bn = blockIdx.y * 128;
  const int sr = t >> 2, sc = (t & 3) << 3;
  const u16* Ag = A + (size_t)(bm + sr) * K + sc;
  const u16* Bg = B + (size_t)(bn + sr) * K + sc;
  u16* Asl = As + wid * 512;
  u16* Bsl = Bs + wid * 512;
  f32x4 acc[4][2];
#pragma unroll
  for (int i = 0; i < 4; i++)
#pragma unroll
    for (int j = 0; j < 2; j++) acc[i][j] = (f32x4){0.f, 0.f, 0.f, 0.f};

  for (int kb = 0; kb < K; kb += 32) {
    __syncthreads();
    gload16(Ag + kb, Asl);
    gload16(Bg + kb, Bsl);
    __syncthreads();
    bf16x8 af[4], bq[2];
#pragma unroll
    for (int mi = 0; mi < 4; mi++)
      af[mi] = *(bf16x8*)&As[(wr * 64 + mi * 16 + l15) * 32 + l4 * 8];
#pragma unroll
    for (int ni = 0; ni < 2; ni++)
      bq[ni] = *(bf16x8*)&Bs[(wc * 32 + ni * 16 + l15) * 32 + l4 * 8];
#pragma unroll
    for (int mi = 0; mi < 4; mi++)
#pragma unroll
      for (int ni = 0; ni < 2; ni++)
        acc[mi][ni] = __builtin_amdgcn_mfma_f32_16x16x32_bf16(af[mi], bq[ni], acc[mi][ni], 0, 0, 0);
  }

  const int cb = bn >> 10;
  const float* bp = (EPI == 0) ? b0 : (cb == 0 ? b0 : (cb == 1 ? b1 : b2));
#pragma unroll
  for (int mi = 0; mi < 4; mi++) {
#pragma unroll
    for (int ni = 0; ni < 2; ni++) {
#pragma unroll
      for (int r = 0; r < 4; r++) {
        int row = bm + wr * 64 + mi * 16 + l4 * 4 + r;
        int col = bn + wc * 32 + ni * 16 + l15;
        float v = acc[mi][ni][r] + bp[col & (DM - 1)];
        if (EPI == 0) {
          outF[(size_t)row * N + col] = v;
        } else {
          int b = row >> 11, s = row & (S_LEN - 1);
          int which = col >> 10, cw = col & (DM - 1);
          int h = cw >> 6, d = cw & (HD - 1);
          outQ[(size_t)which * 4194304 +
               (((size_t)(b * NH + h)) * S_LEN + s) * HD + d] = f2b(v);
        }
      }
    }
  }
}

// ---------------- V transpose: [BH][S][64] -> [BH][64][S] (R4-proven) -------
__global__ __launch_bounds__(256)
void transpose_v(const u16* __restrict__ V, u16* __restrict__ Vt) {
  const int bh = blockIdx.y;
  const int s0 = blockIdx.x * 64;
  __shared__ u16 tile[64][72];
  const int t = threadIdx.x;
  const u16* src = V + ((size_t)bh * S_LEN + s0) * HD;
#pragma unroll
  for (int i = 0; i < 2; i++) {
    int e = t * 8 + i * 2048;
    int r = e >> 6, c = e & 63;
    *(bf16x8*)&tile[r][c] = *(const bf16x8*)(src + e);
  }
  __syncthreads();
  u16* dst = Vt + (size_t)bh * HD * S_LEN + s0;
#pragma unroll
  for (int i = 0; i < 2; i++) {
    int e = t * 8 + i * 2048;
    int d = e >> 6, s = e & 63;
    bf16x8 tmp;
#pragma unroll
    for (int j = 0; j < 8; j++) tmp[j] = (short)tile[s + j][d];
    *(bf16x8*)&dst[(size_t)d * S_LEN + s] = tmp;
  }
}

// ---------------- attention: 16x16 MFMA, 16 q-rows/wave, LDS-staged ---------
// Block = 4 waves = 64 q-rows of one bh. Wave w: rows qw=q0+16w.
// S^T = mfma(K,Q) per 16-key subtile f: lane(l15,hi=lane>>4) holds
//   S^T[k=kb+16f+4hi+r][q=qw+l15]  (16x16x32 C-layout, R2-proven).
// PV sigma map: slot i of kchunk kc: k=32kc+16(i>>2)+4hi+(i&3); P B-frag = own
// regs packed; V A-frag loaded with same sigma (R4-proven trick).
// K/V staged in LDS (R8-proven st-16 XOR swizzle, rule #21), double-buffered.

// stage one 64-key tile: K rows contiguous (8KB), Vt rows strided 4096B.
__device__ __forceinline__ void stage_tiles(const char* __restrict__ Kg,
                                            const char* __restrict__ Vg,
                                            u16* __restrict__ Kl, u16* __restrict__ Vl,
                                            int t) {
#pragma unroll
  for (int shot = 0; shot < 2; shot++) {
    int o = shot * 4096 + t * 16;
    int sw = ((o >> 7) & 7) << 4;
    gload16(Kg + (o ^ sw), (char*)Kl + o);
    gload16(Vg + (size_t)(o >> 7) * 4096 + ((o & 127) ^ sw), (char*)Vl + o);
  }
}

__device__ __forceinline__ void process_tile16(
    int kb, const u16* __restrict__ Kl, const u16* __restrict__ Vl,
    const bf16x8 qf[2], const float c16[16],
    int qw, int l15, int hi, float slope2, float qks,
    float& m, float& lsum, f32x4 O[4]) {
  const int x = l15 & 7;
  // ---- S^T: per key-subtile f, accumulate over 2 d-steps ----
  f32x4 st[4];
#pragma unroll
  for (int f = 0; f < 4; f++) st[f] = (f32x4){0.f, 0.f, 0.f, 0.f};
#pragma unroll
  for (int ks = 0; ks < 2; ks++)
#pragma unroll
    for (int f = 0; f < 4; f++) {
      bf16x8 kf = *(const bf16x8*)&Kl[(16 * f + l15) * 64 + (((4 * ks + hi) ^ x) << 3)];
      st[f] = __builtin_amdgcn_mfma_f32_16x16x32_bf16(kf, qf[ks], st[f], 0, 0, 0);
    }

  // ---- scores (exp2 domain), hoisted alibi ----
  const int dkb = kb + 4 * hi - (qw + l15);
  const float base = slope2 * (float)dkb;
  const bool interior = (kb + 63 <= qw) && (kb - (qw + 15) > -WIN);
  float p[16];
  if (interior) {
#pragma unroll
    for (int f = 0; f < 4; f++)
#pragma unroll
      for (int r = 0; r < 4; r++)
        p[4 * f + r] = fmaf(st[f][r], qks, base + c16[4 * f + r]);
  } else {
#pragma unroll
    for (int f = 0; f < 4; f++)
#pragma unroll
      for (int r = 0; r < 4; r++) {
        int dk = dkb + 16 * f + r;
        float s = fmaf(st[f][r], qks, base + c16[4 * f + r]);
        p[4 * f + r] = (dk > 0 || dk <= -WIN) ? -3e38f : s;
      }
  }

  // ---- row max (within-lane tree + 2 cross-hi shuffles) ----
  float t8[8];
#pragma unroll
  for (int r = 0; r < 8; r++) t8[r] = fmaxf(p[r], p[r + 8]);
#pragma unroll
  for (int r = 0; r < 4; r++) t8[r] = fmaxf(t8[r], t8[r + 4]);
  float rmax = fmaxf(fmaxf(t8[0], t8[1]), fmaxf(t8[2], t8[3]));
  rmax = fmaxf(rmax, __shfl_xor(rmax, 16, 64));
  rmax = fmaxf(rmax, __shfl_xor(rmax, 32, 64));

  // ---- defer-max (T13): rescale only when max grew past threshold ----
  if (!__all(rmax <= m + 8.f)) {
    float mn = fmaxf(m, rmax);
    float sc = exp2f(m - mn);
    m = mn;
    lsum *= sc;
#pragma unroll
    for (int d = 0; d < 4; d++)
#pragma unroll
      for (int r = 0; r < 4; r++) O[d][r] *= sc;
  }

  // ---- exp + row sum ----
#pragma unroll
  for (int r = 0; r < 16; r++) p[r] = exp2f(p[r] - m);
  float a8[8];
#pragma unroll
  for (int r = 0; r < 8; r++) a8[r] = p[r] + p[r + 8];
#pragma unroll
  for (int r = 0; r < 4; r++) a8[r] += a8[r + 4];
  float rsum = (a8[0] + a8[1]) + (a8[2] + a8[3]);
  rsum += __shfl_xor(rsum, 16, 64);
  rsum += __shfl_xor(rsum, 32, 64);
  lsum += rsum;

  // ---- P B-frags: own regs packed (sigma) ----
  bf16x8 pb[2];
#pragma unroll
  for (int kc = 0; kc < 2; kc++) {
    u32x4 w4;
    w4[0] = cvt_pk_bf16(p[8 * kc + 0], p[8 * kc + 1]);
    w4[1] = cvt_pk_bf16(p[8 * kc + 2], p[8 * kc + 3]);
    w4[2] = cvt_pk_bf16(p[8 * kc + 4], p[8 * kc + 5]);
    w4[3] = cvt_pk_bf16(p[8 * kc + 6], p[8 * kc + 7]);
    pb[kc] = __builtin_bit_cast(bf16x8, w4);
  }

  // ---- PV: O^T += V^T . P^T  (V A-frag via sigma from swizzled LDS) ----
#pragma unroll
  for (int d = 0; d < 4; d++) {
#pragma unroll
    for (int kc = 0; kc < 2; kc++) {
      const int row = (16 * d + l15) * 64;
      bf16x4 a = *(const bf16x4*)&Vl[row + (((4 * kc + (hi >> 1)) ^ x) << 3) + 4 * (hi & 1)];
      bf16x4 bql = *(const bf16x4*)&Vl[row + (((4 * kc + 2 + (hi >> 1)) ^ x) << 3) + 4 * (hi & 1)];
      bf16x8 vf;
      vf[0] = a[0]; vf[1] = a[1]; vf[2] = a[2]; vf[3] = a[3];
      vf[4] = bql[0]; vf[5] = bql[1]; vf[6] = bql[2]; vf[7] = bql[3];
      O[d] = __builtin_amdgcn_mfma_f32_16x16x32_bf16(vf, pb[kc], O[d], 0, 0, 0);
    }
  }
}

__global__ __launch_bounds__(256, 4)
void attn_kernel(const u16* __restrict__ Q, const u16* __restrict__ Kg,
                 const u16* __restrict__ Vt, u16* __restrict__ attn) {
  __shared__ __align__(16) u16 Klds[2][4096];
  __shared__ __align__(16) u16 Vlds[2][4096];
  const int bid = blockIdx.x;
  const int job = (bid & 7) * 128 + (bid >> 3);  // XCD swizzle (1024 % 8 == 0)
  const int bh = job >> 5, qb = job & 31;
  const int b = bh >> 4, h = bh & 15;
  const int tid = threadIdx.x;
  const int wid = tid >> 6, lane = tid & 63;
  const int l15 = lane & 15, hi = lane >> 4;
  const int q0 = qb << 6;
  const int qw = q0 + 16 * wid;
  const u16* Qp = Q + (size_t)bh * (S_LEN * HD);
  const char* Kbase = (const char*)(Kg + (size_t)bh * (S_LEN * HD));
  const char* Vbase = (const char*)(Vt + (size_t)bh * (HD * S_LEN));

  bf16x8 qf[2];
#pragma unroll
  for (int ks = 0; ks < 2; ks++)
    qf[ks] = *(const bf16x8*)(Qp + (size_t)(qw + l15) * HD + 32 * ks + 8 * hi);

  const float slope2 = exp2f(-0.5f * (float)(h + 1)) * 1.44269504f;
  const float qks = 0.125f * 1.44269504f;
  float c16[16];
#pragma unroll
  for (int f = 0; f < 4; f++)
#pragma unroll
    for (int r = 0; r < 4; r++) c16[4 * f + r] = slope2 * (float)(16 * f + r);

  float m = -1e30f, lsum = 0.f;
  f32x4 O[4];
#pragma unroll
  for (int d = 0; d < 4; d++) O[d] = (f32x4){0.f, 0.f, 0.f, 0.f};

  // block-union tile range; per-wave active range
  int lo_u = q0 - (WIN - 1); if (lo_u < 0) lo_u = 0; lo_u &= ~63;
  const int hi_u = q0;
  int lo_w = qw - (WIN - 1); if (lo_w < 0) lo_w = 0; lo_w &= ~63;
  const int last_w = (qw + 15) & ~63;

  stage_tiles(Kbase + (size_t)lo_u * 128, Vbase + (size_t)lo_u * 2,
              Klds[0], Vlds[0], tid);
  int cur = 0;
  for (int kb = lo_u; kb <= hi_u; kb += 64) {
    __syncthreads();   // tile kb resident; prior reads of buf[cur^1] done
    if (kb + 64 <= hi_u)
      stage_tiles(Kbase + (size_t)(kb + 64) * 128, Vbase + (size_t)(kb + 64) * 2,
                  Klds[cur ^ 1], Vlds[cur ^ 1], tid);
    if (kb >= lo_w && kb <= last_w)    // wave-uniform branch
      process_tile16(kb, Klds[cur], Vlds[cur], qf, c16,
                     qw, l15, hi, slope2, qks, m, lsum, O);
    cur ^= 1;
  }

  const float invl = 1.f / lsum;
  u16* op = attn + ((size_t)(b * S_LEN) + qw + l15) * DM + h * HD + 4 * hi;
#pragma unroll
  for (int d = 0; d < 4; d++) {
    u32x2 w;
    w[0] = cvt_pk_bf16(O[d][0] * invl, O[d][1] * invl);
    w[1] = cvt_pk_bf16(O[d][2] * invl, O[d][3] * invl);
    *(u32x2*)(op + d * 16) = w;
  }
}

// ---------------- launch ----------------
extern "C" void kernel_launch(void* const* d_in, const int* in_sizes, int n_in,
                              void* d_out, int out_size, void* d_ws, size_t ws_size,
                              hipStream_t stream) {
  const float* x  = (const float*)d_in[0];
  const float* wq = (const float*)d_in[1];
  const float* bq = (const float*)d_in[2];
  const float* wk = (const float*)d_in[3];
  const float* bk = (const float*)d_in[4];
  const float* wv = (const float*)d_in[5];
  const float* bv = (const float*)d_in[6];
  const float* wo = (const float*)d_in[7];
  const float* bo = (const float*)d_in[8];

  char* ws = (char*)d_ws;
  u16* xb    = (u16*)(ws);                  // 8 MB  [4096][1024]
  u16* wqkvb = (u16*)(ws + 8388608);        // 6 MB  [3072][1024]
  u16* wob   = (u16*)(ws + 14680064);       // 2 MB  [1024][1024]
  u16* QKVb  = (u16*)(ws + 16777216);       // 24 MB: Q|K|V row layout [bh][s][64]
  u16* Vtb   = (u16*)(ws + 41943040);       // 8 MB  [BH][64][S]
  u16* Ab    = (u16*)(ws + 50331648);       // 8 MB  [B*S][1024]
  u16* Vb    = QKVb + 2 * 4194304;

  const int M = 4096;

  cvt_kernel<<<dim3(4096), dim3(256), 0, stream>>>(x, xb, 4194304);
  cvt_kernel<<<dim3(1024), dim3(256), 0, stream>>>(wq, wqkvb,           1048576);
  cvt_kernel<<<dim3(1024), dim3(256), 0, stream>>>(wk, wqkvb + 1048576, 1048576);
  cvt_kernel<<<dim3(1024), dim3(256), 0, stream>>>(wv, wqkvb + 2097152, 1048576);
  cvt_kernel<<<dim3(1024), dim3(256), 0, stream>>>(wo, wob,             1048576);

  gemm_nt<1><<<dim3(32, 24), dim3(512), 0, stream>>>(xb, wqkvb, bq, bk, bv,
                                                     nullptr, QKVb, M, 3072, DM);

  transpose_v<<<dim3(32, 32), dim3(256), 0, stream>>>(Vb, Vtb);

  attn_kernel<<<dim3(1024), dim3(256), 0, stream>>>(QKVb, QKVb + 4194304, Vtb, Ab);

  gemm_nt<0><<<dim3(32, 8), dim3(512), 0, stream>>>(Ab, wob, bo, nullptr, nullptr,
                                                    (float*)d_out, nullptr, M, DM, DM);
}